// Round 3
// baseline (62.343 us; speedup 1.0000x reference)
//
#include <hip/hip_runtime.h>

#define BS 1024
#define D 1024
#define NEG 32
#define TEMP_INV 20.0f
#define CLS_WEIGHT 0.2f
#define EPS 1e-8f

// One block (512 threads = 8 waves) per batch row; all 1024 blocks are
// co-resident (4 blocks/CU x 256 CU), so the kernel runs in a single round
// with no inter-round tail. Each wave holds the full q row in 16 VGPRs and
// owns 4 similarity vectors (wave 0 additionally owns the 33rd) -> ~20
// independent b128 loads in flight per wave. The final mean is fused via a
// last-block-done atomic pattern in d_ws (acc + counter, re-armed by an
// 8-byte memset each call).
__global__ __launch_bounds__(512) void cls_contrast_fused_kernel(
    const float* __restrict__ q,      // [BS, D]
    const float* __restrict__ p,      // [BS, D]
    const float* __restrict__ neg,    // [BS*NEG, D]
    float* __restrict__ acc_ws,       // d_ws: [0]=float acc, [1]=uint counter
    float* __restrict__ out)          // [1]
{
    const int b    = blockIdx.x;
    const int tid  = threadIdx.x;
    const int lane = tid & 63;
    const int wave = tid >> 6;        // 0..7

    __shared__ float sim_sh[33];

    // ---- q row into registers (wave-redundant; L1 hit after first wave) ----
    const float4* q4 = reinterpret_cast<const float4*>(q + (size_t)b * D);
    float4 qv[4];
    #pragma unroll
    for (int j = 0; j < 4; ++j) qv[j] = q4[lane + j * 64];

    // ---- wave w owns vectors {4w..4w+3}; wave 0 also owns vector 32 ----
    const float4* vp[4];
    #pragma unroll
    for (int k = 0; k < 4; ++k) {
        const int v = 4 * wave + k;
        vp[k] = reinterpret_cast<const float4*>(
            (v == 0) ? (p + (size_t)b * D)
                     : (neg + ((size_t)b * NEG + (size_t)(v - 1)) * (size_t)D));
    }
    const float4* vp4 = reinterpret_cast<const float4*>(
        neg + ((size_t)b * NEG + 31) * (size_t)D);
    const bool has5 = (wave == 0);

    float qn = 0.f;
    float s[4] = {0.f, 0.f, 0.f, 0.f};
    float n[4] = {0.f, 0.f, 0.f, 0.f};
    float s4 = 0.f, n4 = 0.f;

    #pragma unroll
    for (int j = 0; j < 4; ++j) {
        const int i4 = lane + j * 64;              // coalesced 16B/lane
        const float4 qq = qv[j];
        qn += qq.x*qq.x + qq.y*qq.y + qq.z*qq.z + qq.w*qq.w;
        #pragma unroll
        for (int k = 0; k < 4; ++k) {
            const float4 a = vp[k][i4];
            s[k] += a.x*qq.x + a.y*qq.y + a.z*qq.z + a.w*qq.w;
            n[k] += a.x*a.x  + a.y*a.y  + a.z*a.z  + a.w*a.w;
        }
        if (has5) {
            const float4 a = vp4[i4];
            s4 += a.x*qq.x + a.y*qq.y + a.z*qq.z + a.w*qq.w;
            n4 += a.x*a.x  + a.y*a.y  + a.z*a.z  + a.w*a.w;
        }
    }

    // ---- interleaved wave reduction: 9 independent shuffles per level ----
    #pragma unroll
    for (int off = 32; off > 0; off >>= 1) {
        qn   += __shfl_down(qn,   off);
        s[0] += __shfl_down(s[0], off);
        n[0] += __shfl_down(n[0], off);
        s[1] += __shfl_down(s[1], off);
        n[1] += __shfl_down(n[1], off);
        s[2] += __shfl_down(s[2], off);
        n[2] += __shfl_down(n[2], off);
        s[3] += __shfl_down(s[3], off);
        n[3] += __shfl_down(n[3], off);
    }
    if (has5) {
        #pragma unroll
        for (int off = 32; off > 0; off >>= 1) {
            s4 += __shfl_down(s4, off);
            n4 += __shfl_down(n4, off);
        }
    }

    if (lane == 0) {
        const float q_norm = fmaxf(sqrtf(qn), EPS);
        #pragma unroll
        for (int k = 0; k < 4; ++k)
            sim_sh[4 * wave + k] =
                (s[k] / (q_norm * fmaxf(sqrtf(n[k]), EPS))) * TEMP_INV;
        if (has5)
            sim_sh[32] = (s4 / (q_norm * fmaxf(sqrtf(n4), EPS))) * TEMP_INV;
    }
    __syncthreads();

    // ---- wave 0: parallel 33-element logsumexp; fused grid reduction ----
    if (wave == 0) {
        const float x = (lane < 33) ? sim_sh[lane] : -1e30f;
        float m = x;
        #pragma unroll
        for (int off = 32; off > 0; off >>= 1)
            m = fmaxf(m, __shfl_down(m, off));
        m = __shfl(m, 0);
        float e = (lane < 33) ? expf(x - m) : 0.f;
        #pragma unroll
        for (int off = 32; off > 0; off >>= 1)
            e += __shfl_down(e, off);

        if (lane == 0) {
            const float row_loss = (m + logf(e)) - sim_sh[0];
            atomicAdd(acc_ws, row_loss);                      // device scope
            __threadfence();
            unsigned* counter = reinterpret_cast<unsigned*>(acc_ws + 1);
            const unsigned old = atomicAdd(counter, 1u);
            if (old == (unsigned)(BS - 1)) {                  // last block
                __threadfence();
                const float total = atomicAdd(acc_ws, 0.0f);  // coherent read
                out[0] = total * (CLS_WEIGHT / (float)BS);
            }
        }
    }
}

extern "C" void kernel_launch(void* const* d_in, const int* in_sizes, int n_in,
                              void* d_out, int out_size, void* d_ws, size_t ws_size,
                              hipStream_t stream) {
    const float* q   = (const float*)d_in[0];   // text_embeddings     [BS*D]
    const float* p   = (const float*)d_in[1];   // text_pos_embeddings [BS*D]
    const float* neg = (const float*)d_in[2];   // text_neg_embeddings [BS*NEG*D]
    float* out = (float*)d_out;
    float* acc = (float*)d_ws;                  // [0]=acc, [1]=counter

    // Re-arm the fused-reduction state every call (d_ws is poisoned once
    // before timing and never re-poisoned between replays).
    hipMemsetAsync(acc, 0, 8, stream);

    cls_contrast_fused_kernel<<<BS, 512, 0, stream>>>(q, p, neg, acc, out);
}

// Round 4
// 30.942 us; speedup vs baseline: 2.0148x; 2.0148x over previous
//
#include <hip/hip_runtime.h>

#define BS 1024
#define D 1024
#define NEG 32
#define TEMP_INV 20.0f
#define CLS_WEIGHT 0.2f
#define EPS 1e-8f

// One block (512 threads = 8 waves) per batch row; all 1024 blocks are
// co-resident (4 blocks/CU x 256 CU) -> single scheduling round. Each wave
// holds the full q row in 16 VGPRs and owns 4 similarity vectors (wave 0
// additionally owns the 33rd). Block ends with ONE plain store of its row
// loss (no global atomics -- R3 showed 2048 same-line atomic RMWs cost
// ~40 us of serialized tail across 8 XCDs).
__global__ __launch_bounds__(512) void cls_sim_kernel(
    const float* __restrict__ q,      // [BS, D]
    const float* __restrict__ p,      // [BS, D]
    const float* __restrict__ neg,    // [BS*NEG, D]
    float* __restrict__ row_loss)     // [BS] in d_ws
{
    const int b    = blockIdx.x;
    const int tid  = threadIdx.x;
    const int lane = tid & 63;
    const int wave = tid >> 6;        // 0..7

    __shared__ float sim_sh[33];

    // ---- q row into registers (wave-redundant; L1 hit after first wave) ----
    const float4* q4 = reinterpret_cast<const float4*>(q + (size_t)b * D);
    float4 qv[4];
    #pragma unroll
    for (int j = 0; j < 4; ++j) qv[j] = q4[lane + j * 64];

    // ---- wave w owns vectors {4w..4w+3}; wave 0 also owns vector 32 ----
    const float4* vp[4];
    #pragma unroll
    for (int k = 0; k < 4; ++k) {
        const int v = 4 * wave + k;
        vp[k] = reinterpret_cast<const float4*>(
            (v == 0) ? (p + (size_t)b * D)
                     : (neg + ((size_t)b * NEG + (size_t)(v - 1)) * (size_t)D));
    }
    const float4* vp4 = reinterpret_cast<const float4*>(
        neg + ((size_t)b * NEG + 31) * (size_t)D);
    const bool has5 = (wave == 0);

    float qn = 0.f;
    float s[4] = {0.f, 0.f, 0.f, 0.f};
    float n[4] = {0.f, 0.f, 0.f, 0.f};
    float s4 = 0.f, n4 = 0.f;

    #pragma unroll
    for (int j = 0; j < 4; ++j) {
        const int i4 = lane + j * 64;              // coalesced 16B/lane
        const float4 qq = qv[j];
        qn += qq.x*qq.x + qq.y*qq.y + qq.z*qq.z + qq.w*qq.w;
        #pragma unroll
        for (int k = 0; k < 4; ++k) {
            const float4 a = vp[k][i4];
            s[k] += a.x*qq.x + a.y*qq.y + a.z*qq.z + a.w*qq.w;
            n[k] += a.x*a.x  + a.y*a.y  + a.z*a.z  + a.w*a.w;
        }
        if (has5) {
            const float4 a = vp4[i4];
            s4 += a.x*qq.x + a.y*qq.y + a.z*qq.z + a.w*qq.w;
            n4 += a.x*a.x  + a.y*a.y  + a.z*a.z  + a.w*a.w;
        }
    }

    // ---- interleaved wave reduction: 9 independent shuffles per level ----
    #pragma unroll
    for (int off = 32; off > 0; off >>= 1) {
        qn   += __shfl_down(qn,   off);
        s[0] += __shfl_down(s[0], off);
        n[0] += __shfl_down(n[0], off);
        s[1] += __shfl_down(s[1], off);
        n[1] += __shfl_down(n[1], off);
        s[2] += __shfl_down(s[2], off);
        n[2] += __shfl_down(n[2], off);
        s[3] += __shfl_down(s[3], off);
        n[3] += __shfl_down(n[3], off);
    }
    if (has5) {
        #pragma unroll
        for (int off = 32; off > 0; off >>= 1) {
            s4 += __shfl_down(s4, off);
            n4 += __shfl_down(n4, off);
        }
    }

    if (lane == 0) {
        const float q_norm = fmaxf(sqrtf(qn), EPS);
        #pragma unroll
        for (int k = 0; k < 4; ++k)
            sim_sh[4 * wave + k] =
                (s[k] / (q_norm * fmaxf(sqrtf(n[k]), EPS))) * TEMP_INV;
        if (has5)
            sim_sh[32] = (s4 / (q_norm * fmaxf(sqrtf(n4), EPS))) * TEMP_INV;
    }
    __syncthreads();

    // ---- wave 0: parallel 33-element logsumexp; one plain store ----
    if (wave == 0) {
        const float x = (lane < 33) ? sim_sh[lane] : -1e30f;
        float m = x;
        #pragma unroll
        for (int off = 32; off > 0; off >>= 1)
            m = fmaxf(m, __shfl_down(m, off));
        m = __shfl(m, 0);
        float e = (lane < 33) ? expf(x - m) : 0.f;
        #pragma unroll
        for (int off = 32; off > 0; off >>= 1)
            e += __shfl_down(e, off);
        if (lane == 0)
            row_loss[b] = (m + logf(e)) - sim_sh[0];
    }
}

// Single-block reduction of the 1024 per-row losses; overwrites out[0]
// directly (no memset, no atomics).
__global__ __launch_bounds__(256) void cls_loss_reduce_kernel(
    const float* __restrict__ row_loss, float* __restrict__ out)
{
    const int tid  = threadIdx.x;
    const int lane = tid & 63;
    const int wave = tid >> 6;

    __shared__ float partial[4];

    const float4 v = reinterpret_cast<const float4*>(row_loss)[tid];
    float s = v.x + v.y + v.z + v.w;
    #pragma unroll
    for (int off = 32; off > 0; off >>= 1)
        s += __shfl_down(s, off);
    if (lane == 0) partial[wave] = s;
    __syncthreads();
    if (tid == 0) {
        const float total = partial[0] + partial[1] + partial[2] + partial[3];
        out[0] = total * (CLS_WEIGHT / (float)BS);
    }
}

extern "C" void kernel_launch(void* const* d_in, const int* in_sizes, int n_in,
                              void* d_out, int out_size, void* d_ws, size_t ws_size,
                              hipStream_t stream) {
    const float* q   = (const float*)d_in[0];   // text_embeddings     [BS*D]
    const float* p   = (const float*)d_in[1];   // text_pos_embeddings [BS*D]
    const float* neg = (const float*)d_in[2];   // text_neg_embeddings [BS*NEG*D]
    float* out      = (float*)d_out;
    float* row_loss = (float*)d_ws;             // BS floats of scratch

    cls_sim_kernel<<<BS, 512, 0, stream>>>(q, p, neg, row_loss);
    cls_loss_reduce_kernel<<<1, 256, 0, stream>>>(row_loss, out);
}